// Round 7
// baseline (776.911 us; speedup 1.0000x reference)
//
#include <hip/hip_runtime.h>
#include <cmath>

// PropConv: K=10 hop gated propagation on a fixed graph + output MLP.
// R14 (hop micro-opt round; hops = 71% of runtime at 54.5us each):
// (1) hop gather batches 8->12-deep (deg~32 = 12+12+8), gate read at shfl
//     time so only cg[12]+v[12] live (~56 VGPR, stays under the 64-VGPR
//     8-waves/SIMD cliff); 32-bit gather addressing.
// (2) reduce+scan1 fused (identical 196-block geometry) -- one fewer pass.
// (3) W1/W2 pre-converted to bf16 once; MLP stages Bs from bf16 (halves
//     per-block W traffic, deletes 16K bf16rne per block).
// Hop traffic model: FETCH 163.7MB/hop vs ~134MB compulsory floor (12.8MB
// state x 8 XCD replicas + feat0 25.6 + epay 6.4); WRITE 12.5MB = g_out.
// If hop doesn't improve with VGPR<=64, it's at the structural limit.

#define NNODES 50000
#define NEDGES 1600000
#define DD 128
#define KHOPS 10
#define ALPHA 0.1f

#define RS 16384          // node-range size (64KB LDS of int counters)
#define NRANGE 4          // ceil(50000/16384)
#define NSLICE 64         // edge slices
#define SLICE_E (NEDGES / NSLICE)   // 25000 edges/slice (100000B, 16B-aligned)

typedef short short8 __attribute__((ext_vector_type(8)));
typedef float f32x4 __attribute__((ext_vector_type(4)));

static __device__ __forceinline__ unsigned bf16rne(float x) {
    unsigned u = __float_as_uint(x);
    return (u + 0x7FFFu + ((u >> 16) & 1u)) >> 16;
}
static __device__ __forceinline__ float bf_lo(unsigned w) { return __uint_as_float(w << 16); }
static __device__ __forceinline__ float bf_hi(unsigned w) { return __uint_as_float(w & 0xFFFF0000u); }

// Parallel 8-entry gate table: thread (t = tid>>5, j = tid&31) computes
// hidden unit j of etype t; width-32 butterfly reduces g*We2 over j.
__global__ __launch_bounds__(256) void gate_kernel(const float* __restrict__ emb,
                                                   const float* __restrict__ We1,
                                                   const float* __restrict__ be1,
                                                   const float* __restrict__ We2,
                                                   const float* __restrict__ be2,
                                                   float* __restrict__ gate) {
    int tid = threadIdx.x;
    int t = tid >> 5, j = tid & 31;
    float a = be1[j];
#pragma unroll 8
    for (int k = 0; k < DD; k++)
        a += emb[t * DD + k] * We1[k * 32 + j];   // We1 row k: lanes j coalesce
    float g = 0.5f * a * (1.0f + erff(a * 0.70710678118654752f));  // exact GELU
    float p = g * We2[j];
#pragma unroll
    for (int m = 16; m >= 1; m >>= 1) p += __shfl_xor(p, m, 32);
    if (j == 0) gate[t] = 1.0f + 1.0f / (1.0f + expf(-(p + be2[0])));  // 1+sigmoid
}

// One-shot f32->bf16 conversion of the MLP weights (16384 each).
__global__ __launch_bounds__(256) void wconv_kernel(const float* __restrict__ W1,
                                                    const float* __restrict__ W2,
                                                    unsigned short* __restrict__ w1b,
                                                    unsigned short* __restrict__ w2b) {
    int i = blockIdx.x * 256 + threadIdx.x;
    if (i < DD * DD) {
        w1b[i] = (unsigned short)bf16rne(W1[i]);
        w2b[i] = (unsigned short)bf16rne(W2[i]);
    }
}

// Pass1a: per-(range,slice) in-degree partial histogram via LDS atomics.
// cnt[b][n] written non-atomically (includes zeros -> no memset needed).
__global__ __launch_bounds__(256) void hist_kernel(const int* __restrict__ key,
                                                   int* __restrict__ cnt) {
    __shared__ int h[RS];
    int b = blockIdx.x, r = blockIdx.y;
    int lo = r * RS;
    int hi = lo + RS; if (hi > NNODES) hi = NNODES;
    for (int i = threadIdx.x; i < RS; i += 256) h[i] = 0;
    __syncthreads();
    const int4* p = (const int4*)(key + b * SLICE_E);
    for (int i = threadIdx.x; i < SLICE_E / 4; i += 256) {
        int4 v = p[i];
        if (v.x >= lo && v.x < hi) atomicAdd(&h[v.x - lo], 1);
        if (v.y >= lo && v.y < hi) atomicAdd(&h[v.y - lo], 1);
        if (v.z >= lo && v.z < hi) atomicAdd(&h[v.z - lo], 1);
        if (v.w >= lo && v.w < hi) atomicAdd(&h[v.w - lo], 1);
    }
    __syncthreads();
    int n = hi - lo;
    for (int i = threadIdx.x; i < n; i += 256)
        cnt[(size_t)b * NNODES + lo + i] = h[i];
}

// Fused: totals over slices (incnt/outcnt) + block-local exclusive scan of
// incnt (excl, bsum). Same 196-block geometry as the old scan1.
__global__ __launch_bounds__(256) void reduce_scan_kernel(const int* __restrict__ cnt_in,
                                                          const int* __restrict__ cnt_out,
                                                          int* __restrict__ incnt,
                                                          int* __restrict__ outcnt,
                                                          int* __restrict__ excl,
                                                          int* __restrict__ bsum, int N) {
    __shared__ int sh[256];
    int t = threadIdx.x;
    int g = blockIdx.x * 256 + t;
    int a = 0, b = 0;
    if (g < N) {
        for (int x = 0; x < NSLICE; x++) {
            a += cnt_in[(size_t)x * NNODES + g];
            b += cnt_out[(size_t)x * NNODES + g];
        }
        incnt[g] = a;
        outcnt[g] = b;
    }
    int v = a;                        // 0 for g >= N
    sh[t] = v;
    __syncthreads();
    for (int off = 1; off < 256; off <<= 1) {
        int u = 0;
        if (t >= off) u = sh[t - off];
        __syncthreads();
        sh[t] += u;
        __syncthreads();
    }
    if (g < N) excl[g] = sh[t] - v;   // exclusive within block
    if (t == 255) bsum[blockIdx.x] = sh[255];
}

__global__ __launch_bounds__(256) void scan2_kernel(int* __restrict__ bsum, int nb) {
    __shared__ int sh[256];
    int t = threadIdx.x;
    int v = (t < nb) ? bsum[t] : 0;
    sh[t] = v;
    __syncthreads();
    for (int off = 1; off < 256; off <<= 1) {
        int u = 0;
        if (t >= off) u = sh[t - off];
        __syncthreads();
        sh[t] += u;
        __syncthreads();
    }
    if (t < nb) bsum[t] = sh[t] - v;         // exclusive
}
__global__ __launch_bounds__(256) void scan3_kernel(const int* __restrict__ excl,
                                                    const int* __restrict__ bsum,
                                                    int* __restrict__ row_ptr, int N, int E) {
    int g = blockIdx.x * 256 + threadIdx.x;
    if (g < N) row_ptr[g] = excl[g] + bsum[g >> 8];
    if (g == N) row_ptr[N] = E;
}

// Per-slice bucket bases: base_part[b][n] = row_ptr[n] + sum_{b'<b} cnt_in[b'][n].
// Sub-ranges partition each dst bucket deterministically by slice.
__global__ __launch_bounds__(256) void base_kernel(const int* __restrict__ row_ptr,
                                                   const int* __restrict__ cnt_in,
                                                   int* __restrict__ base_part, int N) {
    int n = blockIdx.x * 256 + threadIdx.x;
    if (n >= N) return;
    int run = row_ptr[n];
    for (int b = 0; b < NSLICE; b++) {
        base_part[(size_t)b * NNODES + n] = run;
        run += cnt_in[(size_t)b * NNODES + n];
    }
}

// Pass2: bucket edges by dst with LDS cursors -- zero global atomics.
// Payload: src (16b) | etype (<<16). Block (r,b) re-streams slice b; each
// in-range edge gets pos = lds_fetch_add(cursor[dst-lo]). Positions are
// unique: cursor range for (b,n) is exactly cnt_in[b][n] wide.
__global__ __launch_bounds__(256) void scatter2_kernel(const int* __restrict__ src,
                                                       const int* __restrict__ dst,
                                                       const int* __restrict__ ef,
                                                       const int* __restrict__ base_part,
                                                       int* __restrict__ epay) {
    __shared__ int cur[RS];
    int b = blockIdx.x, r = blockIdx.y;
    int lo = r * RS;
    int hi = lo + RS; if (hi > NNODES) hi = NNODES;
    int n = hi - lo;
    for (int i = threadIdx.x; i < n; i += 256)
        cur[i] = base_part[(size_t)b * NNODES + lo + i];
    __syncthreads();
    int off = b * SLICE_E;
    const int4* pd = (const int4*)(dst + off);
    const int4* ps = (const int4*)(src + off);
    const int4* pf = (const int4*)(ef + off);
    for (int i = threadIdx.x; i < SLICE_E / 4; i += 256) {
        int4 d = pd[i];
        int4 s = ps[i];
        int4 f = pf[i];
        int dv[4] = {d.x, d.y, d.z, d.w};
        int sv[4] = {s.x, s.y, s.z, s.w};
        int fv[4] = {f.x, f.y, f.z, f.w};
#pragma unroll
        for (int u = 0; u < 4; u++) {
            if (dv[u] >= lo && dv[u] < hi) {
                int pos = atomicAdd(&cur[dv[u] - lo], 1);
                epay[pos] = sv[u] | (fv[u] << 16);
            }
        }
    }
}

// g0 = bf16(feat * src_norm), row-major [N][128] bf16 (256B rows).
__global__ void scale_kernel(const float* __restrict__ feat, const int* __restrict__ outcnt,
                             unsigned* __restrict__ g0, int N) {
    int i = blockIdx.x * blockDim.x + threadIdx.x;   // one float4-group (4 cols)
    if (i >= N * 32) return;
    int row = i >> 5;
    int oc = outcnt[row]; if (oc < 1) oc = 1;
    float sn = rsqrtf((float)oc);
    float4 v = ((const float4*)feat)[i];
    uint2 o;
    o.x = bf16rne(v.x * sn) | (bf16rne(v.y * sn) << 16);
    o.y = bf16rne(v.z * sn) | (bf16rne(v.w * sn) << 16);
    ((uint2*)g0)[i] = o;
}

// Half-wave (32 lanes) per dst node; lane holds uint2 = 4 bf16 cols of the
// 256B row. Payloads loaded coalesced in chunks of 32, broadcast via __shfl;
// 12-deep batches (deg~32 = 12+12+8): gate fetched at shfl time so only
// cg[12]+v[12] stay live across the gather (~56 VGPR, 8 waves/SIMD kept).
// Epilogue f32: h = .9*dn*agg + .1*feat0; stores bf16(h*sn) (last: bf16(h)).
__global__ __launch_bounds__(256) void hop_kernel(const unsigned* __restrict__ g_in,
                                                  const float* __restrict__ feat0,
                                                  const int* __restrict__ incnt,
                                                  const int* __restrict__ outcnt,
                                                  const float* __restrict__ gate_g,
                                                  const int* __restrict__ row_ptr,
                                                  const int* __restrict__ epay,
                                                  unsigned* __restrict__ g_out,
                                                  int N, int last) {
    __shared__ float gateL[8];
    if (threadIdx.x < 8) gateL[threadIdx.x] = gate_g[threadIdx.x];
    __syncthreads();
    int half = threadIdx.x >> 5;     // 0..7
    int lane = threadIdx.x & 31;
    int node = blockIdx.x * 8 + half;
    if (node >= N) return;
    int beg = row_ptr[node], end = row_ptr[node + 1];
    const uint2* gp = (const uint2*)g_in;            // row = 32 uint2
    float a0 = 0.f, a1 = 0.f, a2 = 0.f, a3 = 0.f;
    for (int base = beg; base < end; base += 32) {
        int n = end - base; if (n > 32) n = 32;
        int p = 0;
        if (lane < n) p = epay[base + lane];
        int j = 0;
        for (; j + 12 <= n; j += 12) {
            float cg[12];
            uint2 v[12];
#pragma unroll
            for (int u = 0; u < 12; u++) {
                int pj = __shfl(p, j + u, 32);
                cg[u] = gateL[(unsigned)pj >> 16];
                v[u] = gp[((unsigned)(pj & 0xFFFF) << 5) + lane];
            }
#pragma unroll
            for (int u = 0; u < 12; u++) {
                a0 += cg[u] * bf_lo(v[u].x); a1 += cg[u] * bf_hi(v[u].x);
                a2 += cg[u] * bf_lo(v[u].y); a3 += cg[u] * bf_hi(v[u].y);
            }
        }
        for (; j + 8 <= n; j += 8) {
            float cg[8];
            uint2 v[8];
#pragma unroll
            for (int u = 0; u < 8; u++) {
                int pj = __shfl(p, j + u, 32);
                cg[u] = gateL[(unsigned)pj >> 16];
                v[u] = gp[((unsigned)(pj & 0xFFFF) << 5) + lane];
            }
#pragma unroll
            for (int u = 0; u < 8; u++) {
                a0 += cg[u] * bf_lo(v[u].x); a1 += cg[u] * bf_hi(v[u].x);
                a2 += cg[u] * bf_lo(v[u].y); a3 += cg[u] * bf_hi(v[u].y);
            }
        }
        for (; j < n; j++) {
            int pj = __shfl(p, j, 32);
            float c = gateL[(unsigned)pj >> 16];
            uint2 v = gp[((unsigned)(pj & 0xFFFF) << 5) + lane];
            a0 += c * bf_lo(v.x); a1 += c * bf_hi(v.x);
            a2 += c * bf_lo(v.y); a3 += c * bf_hi(v.y);
        }
    }
    int ic = incnt[node]; if (ic < 1) ic = 1;
    float dn = rsqrtf((float)ic) * (1.0f - ALPHA);
    float4 fv = *(const float4*)(feat0 + (size_t)node * DD + lane * 4);
    float h0 = dn * a0 + ALPHA * fv.x;
    float h1 = dn * a1 + ALPHA * fv.y;
    float h2 = dn * a2 + ALPHA * fv.z;
    float h3 = dn * a3 + ALPHA * fv.w;
    float sc = 1.0f;
    if (!last) { int oc = outcnt[node]; if (oc < 1) oc = 1; sc = rsqrtf((float)oc); }
    uint2 o;
    o.x = bf16rne(h0 * sc) | (bf16rne(h1 * sc) << 16);
    o.y = bf16rne(h2 * sc) | (bf16rne(h3 * sc) << 16);
    ((uint2*)g_out)[(size_t)node * 32 + lane] = o;
}

// bf16 MFMA MLP layer: out[N,128] = act(in[N,128] @ W[128,128] + b).
// W comes in pre-converted bf16 (wconv_kernel). Block = 256 thr (4 waves),
// 64-row tile, full K=128 and all 128 cols. Verified gfx950 layouts:
// A[m=lane&15][k=quad*8+j], B[k][n=lane&15], D col=lane&15, row=quad*4+reg.
#define ASTR 136
__global__ __launch_bounds__(256) void mlp_mfma_kernel(const unsigned short* __restrict__ in,
                                                       const unsigned short* __restrict__ Wb,
                                                       const float* __restrict__ bias,
                                                       void* __restrict__ outp,
                                                       int N, int mode) {  // mode0: gelu+bf16 out; mode1: f32 out
    __shared__ unsigned short As[64 * ASTR];    // 17.4 KB
    __shared__ unsigned short Bs[128 * ASTR];   // 34.8 KB
    int tid = threadIdx.x;
    int row0 = blockIdx.x * 64;
    // stage A: 64 rows x 128 bf16 (clamp rows >= N)
    for (int i = tid; i < 64 * 16; i += 256) {
        int r = i >> 4, c8 = i & 15;
        int gr = row0 + r; if (gr >= N) gr = N - 1;
        uint4 v = *(const uint4*)(in + (size_t)gr * DD + c8 * 8);
        *(uint4*)&As[r * ASTR + c8 * 8] = v;
    }
    // stage B transposed: Bs[n][k] = Wb[k][n] (bf16 already)
    for (int i = tid; i < 128 * 128; i += 256) {
        int k = i >> 7, n = i & 127;
        Bs[n * ASTR + k] = Wb[i];
    }
    __syncthreads();

    int wv = tid >> 6, lane = tid & 63;
    int m = lane & 15, quad = lane >> 4;
    const unsigned short* arow = &As[(16 * wv + m) * ASTR + quad * 8];
    f32x4 acc[8];
#pragma unroll
    for (int t = 0; t < 8; t++) {
        const unsigned short* brow = &Bs[(t * 16 + m) * ASTR + quad * 8];
        f32x4 c = {0.f, 0.f, 0.f, 0.f};
#pragma unroll
        for (int s = 0; s < 4; s++) {
            short8 a = *(const short8*)(arow + s * 32);
            short8 b = *(const short8*)(brow + s * 32);
            c = __builtin_amdgcn_mfma_f32_16x16x32_bf16(a, b, c, 0, 0, 0);
        }
        acc[t] = c;
    }
#pragma unroll
    for (int t = 0; t < 8; t++) {
        float bv = bias[t * 16 + m];
#pragma unroll
        for (int r = 0; r < 4; r++) {
            int grow = row0 + 16 * wv + quad * 4 + r;
            if (grow >= N) continue;
            float v = acc[t][r] + bv;
            size_t oidx = (size_t)grow * DD + t * 16 + m;
            if (mode == 0) {
                v = 0.5f * v * (1.0f + erff(v * 0.70710678118654752f));
                ((unsigned short*)outp)[oidx] = (unsigned short)bf16rne(v);
            } else {
                ((float*)outp)[oidx] = v;
            }
        }
    }
}

extern "C" void kernel_launch(void* const* d_in, const int* in_sizes, int n_in,
                              void* d_out, int out_size, void* d_ws, size_t ws_size,
                              hipStream_t stream) {
    const float* feat = (const float*)d_in[0];
    const int*   e_feat = (const int*)d_in[1];
    const int*   src = (const int*)d_in[2];
    const int*   dst = (const int*)d_in[3];
    const float* emb = (const float*)d_in[4];
    const float* We1 = (const float*)d_in[5];
    const float* be1 = (const float*)d_in[6];
    const float* We2 = (const float*)d_in[7];
    const float* be2 = (const float*)d_in[8];
    const float* W1  = (const float*)d_in[9];
    const float* b1  = (const float*)d_in[10];
    const float* W2  = (const float*)d_in[11];
    const float* b2  = (const float*)d_in[12];
    float* out = (float*)d_out;

    const int N = NNODES, E = NEDGES;
    const int NBLK = (N + 255) / 256;     // 196 scan/reduce blocks
    char* ws = (char*)d_ws;
    size_t off = 0;
    unsigned* ga = (unsigned*)(ws + off);  off += (size_t)N * 256;        // 12.8 MB bf16 state
    unsigned* gb = (unsigned*)(ws + off);  off += (size_t)N * 256;        // 12.8 MB bf16 state
    int*   epay = (int*)(ws + off);        off += (size_t)E * 4;          // 6.4 MB
    int*   row_ptr = (int*)(ws + off);     off += (size_t)(N + 1) * 4;
    int*   excl = (int*)(ws + off);        off += (size_t)N * 4;
    int*   bsum = (int*)(ws + off);        off += 256 * 4;
    int*   cnts = (int*)(ws + off);        off += (size_t)2 * N * 4;      // incnt|outcnt
    int*   cnt_in = (int*)(ws + off);      off += (size_t)NSLICE * N * 4; // 12.8 MB partials
    int*   cnt_out = (int*)(ws + off);     off += (size_t)NSLICE * N * 4; // 12.8 MB partials
    int*   base_part = (int*)(ws + off);   off += (size_t)NSLICE * N * 4; // 12.8 MB bases
    unsigned short* w1b = (unsigned short*)(ws + off); off += (size_t)DD * DD * 2;
    unsigned short* w2b = (unsigned short*)(ws + off); off += (size_t)DD * DD * 2;
    float* gate = (float*)(ws + off);      off += 64;
    int* incnt  = cnts;
    int* outcnt = cnts + N;

    // No memsets needed: hist writes full partial slabs (incl. zeros).
    gate_kernel<<<1, 256, 0, stream>>>(emb, We1, be1, We2, be2, gate);
    wconv_kernel<<<(DD * DD + 255) / 256, 256, 0, stream>>>(W1, W2, w1b, w2b);
    dim3 hg(NSLICE, NRANGE);
    hist_kernel<<<hg, 256, 0, stream>>>(dst, cnt_in);
    hist_kernel<<<hg, 256, 0, stream>>>(src, cnt_out);
    reduce_scan_kernel<<<NBLK, 256, 0, stream>>>(cnt_in, cnt_out, incnt, outcnt,
                                                 excl, bsum, N);
    scan2_kernel<<<1, 256, 0, stream>>>(bsum, NBLK);
    scan3_kernel<<<(N + 256) / 256 + 1, 256, 0, stream>>>(excl, bsum, row_ptr, N, E);
    base_kernel<<<(N + 255) / 256, 256, 0, stream>>>(row_ptr, cnt_in, base_part, N);
    scatter2_kernel<<<hg, 256, 0, stream>>>(src, dst, e_feat, base_part, epay);
    scale_kernel<<<(N * 32 + 255) / 256, 256, 0, stream>>>(feat, outcnt, ga, N);

    const unsigned* gin = ga;
    unsigned* gout = gb;
    for (int k = 0; k < KHOPS; k++) {
        int last = (k == KHOPS - 1);
        hop_kernel<<<(N + 7) / 8, 256, 0, stream>>>(gin, feat, incnt, outcnt, gate,
                                                    row_ptr, epay, gout, N, last);
        gin = gout;
        gout = (gout == ga) ? gb : ga;
    }
    // Final h (unscaled, bf16) is in ga (hop9 writes ga); gb is free -> hidden.
    const unsigned short* hfin = (const unsigned short*)gin;
    unsigned short* hidden = (unsigned short*)gout;
    mlp_mfma_kernel<<<(N + 63) / 64, 256, 0, stream>>>(hfin, w1b, b1, hidden, N, 0);
    mlp_mfma_kernel<<<(N + 63) / 64, 256, 0, stream>>>(hidden, w2b, b2, out, N, 1);
}

// Round 8
// 758.547 us; speedup vs baseline: 1.0242x; 1.0242x over previous
//
#include <hip/hip_runtime.h>
#include <cmath>

// PropConv: K=10 hop gated propagation on a fixed graph + output MLP.
// R15 (traffic cuts; hop core accepted at the L3 random-gather ceiling after
// R14's ILP null result -- 410MB logical gather / 54.4us = 7.5TB/s):
// (1) residual stream bf16: af0 = bf16(ALPHA*feat0) precomputed; hop reads
//     uint2 instead of float4 (-12.8MB FETCH/hop of 163.7).
// (2) hist: ONE kernel, dual 64KB LDS histograms (128KB static LDS, proven
//     on gfx950), packed 2xu16-per-word LDS atomicAdd (counts<2^16, no carry
//     bleed); RS=32768, NRANGE=2 -> edge streaming 51.2->25.6MB.
// (3) scatter2: RS=32768 int cursors (128KB LDS), NRANGE=2 -> 76.8->38.4MB.
// (4) scan3 fused into base_kernel.
// If hop stays ~54us, it is structurally bound (mixed 41% HBM / 41% VALU /
// L3-gather ceiling) and the kernel is at its roofline.

#define NNODES 50000
#define NEDGES 1600000
#define DD 128
#define KHOPS 10
#define ALPHA 0.1f

#define RS 32768          // node-range size
#define NRANGE 2          // ceil(50000/32768)
#define NSLICE 64         // edge slices
#define SLICE_E (NEDGES / NSLICE)   // 25000 edges/slice

typedef short short8 __attribute__((ext_vector_type(8)));
typedef float f32x4 __attribute__((ext_vector_type(4)));

static __device__ __forceinline__ unsigned bf16rne(float x) {
    unsigned u = __float_as_uint(x);
    return (u + 0x7FFFu + ((u >> 16) & 1u)) >> 16;
}
static __device__ __forceinline__ float bf_lo(unsigned w) { return __uint_as_float(w << 16); }
static __device__ __forceinline__ float bf_hi(unsigned w) { return __uint_as_float(w & 0xFFFF0000u); }

// Parallel 8-entry gate table: thread (t = tid>>5, j = tid&31) computes
// hidden unit j of etype t; width-32 butterfly reduces g*We2 over j.
__global__ __launch_bounds__(256) void gate_kernel(const float* __restrict__ emb,
                                                   const float* __restrict__ We1,
                                                   const float* __restrict__ be1,
                                                   const float* __restrict__ We2,
                                                   const float* __restrict__ be2,
                                                   float* __restrict__ gate) {
    int tid = threadIdx.x;
    int t = tid >> 5, j = tid & 31;
    float a = be1[j];
#pragma unroll 8
    for (int k = 0; k < DD; k++)
        a += emb[t * DD + k] * We1[k * 32 + j];   // We1 row k: lanes j coalesce
    float g = 0.5f * a * (1.0f + erff(a * 0.70710678118654752f));  // exact GELU
    float p = g * We2[j];
#pragma unroll
    for (int m = 16; m >= 1; m >>= 1) p += __shfl_xor(p, m, 32);
    if (j == 0) gate[t] = 1.0f + 1.0f / (1.0f + expf(-(p + be2[0])));  // 1+sigmoid
}

// One-shot f32->bf16 conversion of the MLP weights (16384 each).
__global__ __launch_bounds__(256) void wconv_kernel(const float* __restrict__ W1,
                                                    const float* __restrict__ W2,
                                                    unsigned short* __restrict__ w1b,
                                                    unsigned short* __restrict__ w2b) {
    int i = blockIdx.x * 256 + threadIdx.x;
    if (i < DD * DD) {
        w1b[i] = (unsigned short)bf16rne(W1[i]);
        w2b[i] = (unsigned short)bf16rne(W2[i]);
    }
}

// Fused dual histogram: block (slice b, range r) streams BOTH dst and src
// slices; packed 2xu16 counters per 32-bit LDS word (atomicAdd of 1 or
// 1<<16; per-slice counts <= 25000 so halves never overflow/carry).
// cnt slabs written non-atomically (full coverage incl. zeros).
__global__ __launch_bounds__(256) void hist_kernel(const int* __restrict__ dst,
                                                   const int* __restrict__ src,
                                                   int* __restrict__ cnt_in,
                                                   int* __restrict__ cnt_out) {
    __shared__ unsigned hin[RS / 2];    // 64 KB
    __shared__ unsigned hout[RS / 2];   // 64 KB
    int b = blockIdx.x, r = blockIdx.y;
    int lo = r * RS;
    int hi = lo + RS; if (hi > NNODES) hi = NNODES;
    for (int i = threadIdx.x; i < RS / 2; i += 256) { hin[i] = 0; hout[i] = 0; }
    __syncthreads();
    const int4* pd = (const int4*)(dst + b * SLICE_E);
    const int4* ps = (const int4*)(src + b * SLICE_E);
    for (int i = threadIdx.x; i < SLICE_E / 4; i += 256) {
        int4 d = pd[i];
        int4 s = ps[i];
        int dv[4] = {d.x, d.y, d.z, d.w};
        int sv[4] = {s.x, s.y, s.z, s.w};
#pragma unroll
        for (int u = 0; u < 4; u++) {
            if (dv[u] >= lo && dv[u] < hi) {
                int k = dv[u] - lo;
                atomicAdd(&hin[k >> 1], 1u << ((k & 1) * 16));
            }
            if (sv[u] >= lo && sv[u] < hi) {
                int k = sv[u] - lo;
                atomicAdd(&hout[k >> 1], 1u << ((k & 1) * 16));
            }
        }
    }
    __syncthreads();
    int n = hi - lo;
    for (int i = threadIdx.x; i < n; i += 256) {
        cnt_in[(size_t)b * NNODES + lo + i]  = (hin[i >> 1]  >> ((i & 1) * 16)) & 0xFFFF;
        cnt_out[(size_t)b * NNODES + lo + i] = (hout[i >> 1] >> ((i & 1) * 16)) & 0xFFFF;
    }
}

// Fused: totals over slices (incnt/outcnt) + block-local exclusive scan of
// incnt (excl, bsum). 196-block geometry.
__global__ __launch_bounds__(256) void reduce_scan_kernel(const int* __restrict__ cnt_in,
                                                          const int* __restrict__ cnt_out,
                                                          int* __restrict__ incnt,
                                                          int* __restrict__ outcnt,
                                                          int* __restrict__ excl,
                                                          int* __restrict__ bsum, int N) {
    __shared__ int sh[256];
    int t = threadIdx.x;
    int g = blockIdx.x * 256 + t;
    int a = 0, b = 0;
    if (g < N) {
        for (int x = 0; x < NSLICE; x++) {
            a += cnt_in[(size_t)x * NNODES + g];
            b += cnt_out[(size_t)x * NNODES + g];
        }
        incnt[g] = a;
        outcnt[g] = b;
    }
    int v = a;                        // 0 for g >= N
    sh[t] = v;
    __syncthreads();
    for (int off = 1; off < 256; off <<= 1) {
        int u = 0;
        if (t >= off) u = sh[t - off];
        __syncthreads();
        sh[t] += u;
        __syncthreads();
    }
    if (g < N) excl[g] = sh[t] - v;   // exclusive within block
    if (t == 255) bsum[blockIdx.x] = sh[255];
}

__global__ __launch_bounds__(256) void scan2_kernel(int* __restrict__ bsum, int nb) {
    __shared__ int sh[256];
    int t = threadIdx.x;
    int v = (t < nb) ? bsum[t] : 0;
    sh[t] = v;
    __syncthreads();
    for (int off = 1; off < 256; off <<= 1) {
        int u = 0;
        if (t >= off) u = sh[t - off];
        __syncthreads();
        sh[t] += u;
        __syncthreads();
    }
    if (t < nb) bsum[t] = sh[t] - v;         // exclusive
}

// Fused scan3+base: row_ptr[n] = excl[n]+bsum[n>>8]; per-slice bucket bases
// base_part[b][n] = row_ptr[n] + sum_{b'<b} cnt_in[b'][n].
__global__ __launch_bounds__(256) void base_kernel(const int* __restrict__ excl,
                                                   const int* __restrict__ bsum,
                                                   const int* __restrict__ cnt_in,
                                                   int* __restrict__ row_ptr,
                                                   int* __restrict__ base_part, int N, int E) {
    int n = blockIdx.x * 256 + threadIdx.x;
    if (n == N) row_ptr[N] = E;
    if (n >= N) return;
    int run = excl[n] + bsum[n >> 8];
    row_ptr[n] = run;
    for (int b = 0; b < NSLICE; b++) {
        base_part[(size_t)b * NNODES + n] = run;
        run += cnt_in[(size_t)b * NNODES + n];
    }
}

// Pass2: bucket edges by dst with 128KB LDS int cursors -- zero global
// atomics. Payload: src (16b) | etype (<<16). Positions unique: cursor range
// for (b,n) is exactly cnt_in[b][n] wide; slice is a function of edge index.
__global__ __launch_bounds__(256) void scatter2_kernel(const int* __restrict__ src,
                                                       const int* __restrict__ dst,
                                                       const int* __restrict__ ef,
                                                       const int* __restrict__ base_part,
                                                       int* __restrict__ epay) {
    __shared__ int cur[RS];             // 128 KB
    int b = blockIdx.x, r = blockIdx.y;
    int lo = r * RS;
    int hi = lo + RS; if (hi > NNODES) hi = NNODES;
    int n = hi - lo;
    for (int i = threadIdx.x; i < n; i += 256)
        cur[i] = base_part[(size_t)b * NNODES + lo + i];
    __syncthreads();
    int off = b * SLICE_E;
    const int4* pd = (const int4*)(dst + off);
    const int4* ps = (const int4*)(src + off);
    const int4* pf = (const int4*)(ef + off);
    for (int i = threadIdx.x; i < SLICE_E / 4; i += 256) {
        int4 d = pd[i];
        int4 s = ps[i];
        int4 f = pf[i];
        int dv[4] = {d.x, d.y, d.z, d.w};
        int sv[4] = {s.x, s.y, s.z, s.w};
        int fv[4] = {f.x, f.y, f.z, f.w};
#pragma unroll
        for (int u = 0; u < 4; u++) {
            if (dv[u] >= lo && dv[u] < hi) {
                int pos = atomicAdd(&cur[dv[u] - lo], 1);
                epay[pos] = sv[u] | (fv[u] << 16);
            }
        }
    }
}

// g0 = bf16(feat * src_norm) and af0 = bf16(ALPHA * feat), both row-major
// [N][128] bf16 (256B rows).
__global__ void scale_kernel(const float* __restrict__ feat, const int* __restrict__ outcnt,
                             unsigned* __restrict__ g0, unsigned* __restrict__ af0, int N) {
    int i = blockIdx.x * blockDim.x + threadIdx.x;   // one float4-group (4 cols)
    if (i >= N * 32) return;
    int row = i >> 5;
    int oc = outcnt[row]; if (oc < 1) oc = 1;
    float sn = rsqrtf((float)oc);
    float4 v = ((const float4*)feat)[i];
    uint2 o, a;
    o.x = bf16rne(v.x * sn) | (bf16rne(v.y * sn) << 16);
    o.y = bf16rne(v.z * sn) | (bf16rne(v.w * sn) << 16);
    a.x = bf16rne(v.x * ALPHA) | (bf16rne(v.y * ALPHA) << 16);
    a.y = bf16rne(v.z * ALPHA) | (bf16rne(v.w * ALPHA) << 16);
    ((uint2*)g0)[i] = o;
    ((uint2*)af0)[i] = a;
}

// Half-wave (32 lanes) per dst node; lane holds uint2 = 4 bf16 cols of the
// 256B row. Payloads loaded coalesced in chunks of 32, broadcast via __shfl;
// 12-deep batches; gate fetched at shfl time. Epilogue f32:
// h = dn*agg + af0 (af0 = bf16(ALPHA*feat0)); stores bf16(h*sn) (last: bf16(h)).
__global__ __launch_bounds__(256) void hop_kernel(const unsigned* __restrict__ g_in,
                                                  const unsigned* __restrict__ af0,
                                                  const int* __restrict__ incnt,
                                                  const int* __restrict__ outcnt,
                                                  const float* __restrict__ gate_g,
                                                  const int* __restrict__ row_ptr,
                                                  const int* __restrict__ epay,
                                                  unsigned* __restrict__ g_out,
                                                  int N, int last) {
    __shared__ float gateL[8];
    if (threadIdx.x < 8) gateL[threadIdx.x] = gate_g[threadIdx.x];
    __syncthreads();
    int half = threadIdx.x >> 5;     // 0..7
    int lane = threadIdx.x & 31;
    int node = blockIdx.x * 8 + half;
    if (node >= N) return;
    int beg = row_ptr[node], end = row_ptr[node + 1];
    const uint2* gp = (const uint2*)g_in;            // row = 32 uint2
    float a0 = 0.f, a1 = 0.f, a2 = 0.f, a3 = 0.f;
    for (int base = beg; base < end; base += 32) {
        int n = end - base; if (n > 32) n = 32;
        int p = 0;
        if (lane < n) p = epay[base + lane];
        int j = 0;
        for (; j + 12 <= n; j += 12) {
            float cg[12];
            uint2 v[12];
#pragma unroll
            for (int u = 0; u < 12; u++) {
                int pj = __shfl(p, j + u, 32);
                cg[u] = gateL[(unsigned)pj >> 16];
                v[u] = gp[((unsigned)(pj & 0xFFFF) << 5) + lane];
            }
#pragma unroll
            for (int u = 0; u < 12; u++) {
                a0 += cg[u] * bf_lo(v[u].x); a1 += cg[u] * bf_hi(v[u].x);
                a2 += cg[u] * bf_lo(v[u].y); a3 += cg[u] * bf_hi(v[u].y);
            }
        }
        for (; j + 8 <= n; j += 8) {
            float cg[8];
            uint2 v[8];
#pragma unroll
            for (int u = 0; u < 8; u++) {
                int pj = __shfl(p, j + u, 32);
                cg[u] = gateL[(unsigned)pj >> 16];
                v[u] = gp[((unsigned)(pj & 0xFFFF) << 5) + lane];
            }
#pragma unroll
            for (int u = 0; u < 8; u++) {
                a0 += cg[u] * bf_lo(v[u].x); a1 += cg[u] * bf_hi(v[u].x);
                a2 += cg[u] * bf_lo(v[u].y); a3 += cg[u] * bf_hi(v[u].y);
            }
        }
        for (; j < n; j++) {
            int pj = __shfl(p, j, 32);
            float c = gateL[(unsigned)pj >> 16];
            uint2 v = gp[((unsigned)(pj & 0xFFFF) << 5) + lane];
            a0 += c * bf_lo(v.x); a1 += c * bf_hi(v.x);
            a2 += c * bf_lo(v.y); a3 += c * bf_hi(v.y);
        }
    }
    int ic = incnt[node]; if (ic < 1) ic = 1;
    float dn = rsqrtf((float)ic) * (1.0f - ALPHA);
    uint2 af = ((const uint2*)af0)[((unsigned)node << 5) + lane];
    float h0 = dn * a0 + bf_lo(af.x);
    float h1 = dn * a1 + bf_hi(af.x);
    float h2 = dn * a2 + bf_lo(af.y);
    float h3 = dn * a3 + bf_hi(af.y);
    float sc = 1.0f;
    if (!last) { int oc = outcnt[node]; if (oc < 1) oc = 1; sc = rsqrtf((float)oc); }
    uint2 o;
    o.x = bf16rne(h0 * sc) | (bf16rne(h1 * sc) << 16);
    o.y = bf16rne(h2 * sc) | (bf16rne(h3 * sc) << 16);
    ((uint2*)g_out)[((unsigned)node << 5) + lane] = o;
}

// bf16 MFMA MLP layer: out[N,128] = act(in[N,128] @ W[128,128] + b).
// W pre-converted bf16. Block = 256 thr (4 waves), 64-row tile, full K=128.
// Verified gfx950 layouts: A[m=lane&15][k=quad*8+j], B[k][n=lane&15],
// D col=lane&15, row=quad*4+reg.
#define ASTR 136
__global__ __launch_bounds__(256) void mlp_mfma_kernel(const unsigned short* __restrict__ in,
                                                       const unsigned short* __restrict__ Wb,
                                                       const float* __restrict__ bias,
                                                       void* __restrict__ outp,
                                                       int N, int mode) {  // mode0: gelu+bf16 out; mode1: f32 out
    __shared__ unsigned short As[64 * ASTR];    // 17.4 KB
    __shared__ unsigned short Bs[128 * ASTR];   // 34.8 KB
    int tid = threadIdx.x;
    int row0 = blockIdx.x * 64;
    // stage A: 64 rows x 128 bf16 (clamp rows >= N)
    for (int i = tid; i < 64 * 16; i += 256) {
        int r = i >> 4, c8 = i & 15;
        int gr = row0 + r; if (gr >= N) gr = N - 1;
        uint4 v = *(const uint4*)(in + (size_t)gr * DD + c8 * 8);
        *(uint4*)&As[r * ASTR + c8 * 8] = v;
    }
    // stage B transposed: Bs[n][k] = Wb[k][n] (bf16 already)
    for (int i = tid; i < 128 * 128; i += 256) {
        int k = i >> 7, n = i & 127;
        Bs[n * ASTR + k] = Wb[i];
    }
    __syncthreads();

    int wv = tid >> 6, lane = tid & 63;
    int m = lane & 15, quad = lane >> 4;
    const unsigned short* arow = &As[(16 * wv + m) * ASTR + quad * 8];
    f32x4 acc[8];
#pragma unroll
    for (int t = 0; t < 8; t++) {
        const unsigned short* brow = &Bs[(t * 16 + m) * ASTR + quad * 8];
        f32x4 c = {0.f, 0.f, 0.f, 0.f};
#pragma unroll
        for (int s = 0; s < 4; s++) {
            short8 a = *(const short8*)(arow + s * 32);
            short8 b = *(const short8*)(brow + s * 32);
            c = __builtin_amdgcn_mfma_f32_16x16x32_bf16(a, b, c, 0, 0, 0);
        }
        acc[t] = c;
    }
#pragma unroll
    for (int t = 0; t < 8; t++) {
        float bv = bias[t * 16 + m];
#pragma unroll
        for (int r = 0; r < 4; r++) {
            int grow = row0 + 16 * wv + quad * 4 + r;
            if (grow >= N) continue;
            float v = acc[t][r] + bv;
            size_t oidx = (size_t)grow * DD + t * 16 + m;
            if (mode == 0) {
                v = 0.5f * v * (1.0f + erff(v * 0.70710678118654752f));
                ((unsigned short*)outp)[oidx] = (unsigned short)bf16rne(v);
            } else {
                ((float*)outp)[oidx] = v;
            }
        }
    }
}

extern "C" void kernel_launch(void* const* d_in, const int* in_sizes, int n_in,
                              void* d_out, int out_size, void* d_ws, size_t ws_size,
                              hipStream_t stream) {
    const float* feat = (const float*)d_in[0];
    const int*   e_feat = (const int*)d_in[1];
    const int*   src = (const int*)d_in[2];
    const int*   dst = (const int*)d_in[3];
    const float* emb = (const float*)d_in[4];
    const float* We1 = (const float*)d_in[5];
    const float* be1 = (const float*)d_in[6];
    const float* We2 = (const float*)d_in[7];
    const float* be2 = (const float*)d_in[8];
    const float* W1  = (const float*)d_in[9];
    const float* b1  = (const float*)d_in[10];
    const float* W2  = (const float*)d_in[11];
    const float* b2  = (const float*)d_in[12];
    float* out = (float*)d_out;

    const int N = NNODES, E = NEDGES;
    const int NBLK = (N + 255) / 256;     // 196 scan/reduce blocks
    char* ws = (char*)d_ws;
    size_t off = 0;
    unsigned* ga = (unsigned*)(ws + off);  off += (size_t)N * 256;        // 12.8 MB bf16 state
    unsigned* gb = (unsigned*)(ws + off);  off += (size_t)N * 256;        // 12.8 MB bf16 state
    unsigned* af0 = (unsigned*)(ws + off); off += (size_t)N * 256;        // 12.8 MB bf16 residual
    int*   epay = (int*)(ws + off);        off += (size_t)E * 4;          // 6.4 MB
    int*   row_ptr = (int*)(ws + off);     off += (size_t)(N + 1) * 4;
    int*   excl = (int*)(ws + off);        off += (size_t)N * 4;
    int*   bsum = (int*)(ws + off);        off += 256 * 4;
    int*   cnts = (int*)(ws + off);        off += (size_t)2 * N * 4;      // incnt|outcnt
    int*   cnt_in = (int*)(ws + off);      off += (size_t)NSLICE * N * 4; // 12.8 MB partials
    int*   cnt_out = (int*)(ws + off);     off += (size_t)NSLICE * N * 4; // 12.8 MB partials
    int*   base_part = (int*)(ws + off);   off += (size_t)NSLICE * N * 4; // 12.8 MB bases
    unsigned short* w1b = (unsigned short*)(ws + off); off += (size_t)DD * DD * 2;
    unsigned short* w2b = (unsigned short*)(ws + off); off += (size_t)DD * DD * 2;
    float* gate = (float*)(ws + off);      off += 64;
    int* incnt  = cnts;
    int* outcnt = cnts + N;

    // No memsets needed: hist writes full partial slabs (incl. zeros).
    gate_kernel<<<1, 256, 0, stream>>>(emb, We1, be1, We2, be2, gate);
    wconv_kernel<<<(DD * DD + 255) / 256, 256, 0, stream>>>(W1, W2, w1b, w2b);
    dim3 hg(NSLICE, NRANGE);
    hist_kernel<<<hg, 256, 0, stream>>>(dst, src, cnt_in, cnt_out);
    reduce_scan_kernel<<<NBLK, 256, 0, stream>>>(cnt_in, cnt_out, incnt, outcnt,
                                                 excl, bsum, N);
    scan2_kernel<<<1, 256, 0, stream>>>(bsum, NBLK);
    base_kernel<<<(N + 256) / 256 + 1, 256, 0, stream>>>(excl, bsum, cnt_in,
                                                         row_ptr, base_part, N, E);
    scatter2_kernel<<<hg, 256, 0, stream>>>(src, dst, e_feat, base_part, epay);
    scale_kernel<<<(N * 32 + 255) / 256, 256, 0, stream>>>(feat, outcnt, ga, af0, N);

    const unsigned* gin = ga;
    unsigned* gout = gb;
    for (int k = 0; k < KHOPS; k++) {
        int last = (k == KHOPS - 1);
        hop_kernel<<<(N + 7) / 8, 256, 0, stream>>>(gin, af0, incnt, outcnt, gate,
                                                    row_ptr, epay, gout, N, last);
        gin = gout;
        gout = (gout == ga) ? gb : ga;
    }
    // Final h (unscaled, bf16) is in ga (hop9 writes ga); gb is free -> hidden.
    const unsigned short* hfin = (const unsigned short*)gin;
    unsigned short* hidden = (unsigned short*)gout;
    mlp_mfma_kernel<<<(N + 63) / 64, 256, 0, stream>>>(hfin, w1b, b1, hidden, N, 0);
    mlp_mfma_kernel<<<(N + 63) / 64, 256, 0, stream>>>(hidden, w2b, b2, out, N, 1);
}

// Round 9
// 747.368 us; speedup vs baseline: 1.0395x; 1.0150x over previous
//
#include <hip/hip_runtime.h>
#include <cmath>

// PropConv: K=10 hop gated propagation on a fixed graph + output MLP.
// R16: revert R15's RS=32768 geometry (128KB LDS -> 1 block/CU, 128-block
// grid, occupancy 3.5%, scatter2 regressed to 54us top-dispatch). RS=16384,
// NRANGE=4: fused dual hist = 2x32KB packed-u16 LDS (64KB, 2 blocks/CU,
// 256 blocks); scatter2 cur[] = 64KB (2 blocks/CU, 256 blocks). All R15
// fusion wins kept: single edge-stream dual histogram, fused scan3+base,
// bf16 af0 residual (hop dropped below 53us), bf16 W for the MLP.
// Hop core accepted: mixed 41% HBM / 41% VALU at the ~7.5TB/s L3 random-
// gather ceiling, ILP-insensitive (R14 null), 256B/edge irreducible at bf16.

#define NNODES 50000
#define NEDGES 1600000
#define DD 128
#define KHOPS 10
#define ALPHA 0.1f

#define RS 16384          // node-range size
#define NRANGE 4          // ceil(50000/16384)
#define NSLICE 64         // edge slices
#define SLICE_E (NEDGES / NSLICE)   // 25000 edges/slice

typedef short short8 __attribute__((ext_vector_type(8)));
typedef float f32x4 __attribute__((ext_vector_type(4)));

static __device__ __forceinline__ unsigned bf16rne(float x) {
    unsigned u = __float_as_uint(x);
    return (u + 0x7FFFu + ((u >> 16) & 1u)) >> 16;
}
static __device__ __forceinline__ float bf_lo(unsigned w) { return __uint_as_float(w << 16); }
static __device__ __forceinline__ float bf_hi(unsigned w) { return __uint_as_float(w & 0xFFFF0000u); }

// Parallel 8-entry gate table: thread (t = tid>>5, j = tid&31) computes
// hidden unit j of etype t; width-32 butterfly reduces g*We2 over j.
__global__ __launch_bounds__(256) void gate_kernel(const float* __restrict__ emb,
                                                   const float* __restrict__ We1,
                                                   const float* __restrict__ be1,
                                                   const float* __restrict__ We2,
                                                   const float* __restrict__ be2,
                                                   float* __restrict__ gate) {
    int tid = threadIdx.x;
    int t = tid >> 5, j = tid & 31;
    float a = be1[j];
#pragma unroll 8
    for (int k = 0; k < DD; k++)
        a += emb[t * DD + k] * We1[k * 32 + j];   // We1 row k: lanes j coalesce
    float g = 0.5f * a * (1.0f + erff(a * 0.70710678118654752f));  // exact GELU
    float p = g * We2[j];
#pragma unroll
    for (int m = 16; m >= 1; m >>= 1) p += __shfl_xor(p, m, 32);
    if (j == 0) gate[t] = 1.0f + 1.0f / (1.0f + expf(-(p + be2[0])));  // 1+sigmoid
}

// One-shot f32->bf16 conversion of the MLP weights (16384 each).
__global__ __launch_bounds__(256) void wconv_kernel(const float* __restrict__ W1,
                                                    const float* __restrict__ W2,
                                                    unsigned short* __restrict__ w1b,
                                                    unsigned short* __restrict__ w2b) {
    int i = blockIdx.x * 256 + threadIdx.x;
    if (i < DD * DD) {
        w1b[i] = (unsigned short)bf16rne(W1[i]);
        w2b[i] = (unsigned short)bf16rne(W2[i]);
    }
}

// Fused dual histogram: block (slice b, range r) streams BOTH dst and src
// slices; packed 2xu16 counters per 32-bit LDS word (atomicAdd of 1 or
// 1<<16; per-slice counts <= 25000 so halves never overflow/carry).
// 2x32KB LDS -> 2 blocks/CU, 256-block grid.
__global__ __launch_bounds__(256) void hist_kernel(const int* __restrict__ dst,
                                                   const int* __restrict__ src,
                                                   int* __restrict__ cnt_in,
                                                   int* __restrict__ cnt_out) {
    __shared__ unsigned hin[RS / 2];    // 32 KB
    __shared__ unsigned hout[RS / 2];   // 32 KB
    int b = blockIdx.x, r = blockIdx.y;
    int lo = r * RS;
    int hi = lo + RS; if (hi > NNODES) hi = NNODES;
    for (int i = threadIdx.x; i < RS / 2; i += 256) { hin[i] = 0; hout[i] = 0; }
    __syncthreads();
    const int4* pd = (const int4*)(dst + b * SLICE_E);
    const int4* ps = (const int4*)(src + b * SLICE_E);
    for (int i = threadIdx.x; i < SLICE_E / 4; i += 256) {
        int4 d = pd[i];
        int4 s = ps[i];
        int dv[4] = {d.x, d.y, d.z, d.w};
        int sv[4] = {s.x, s.y, s.z, s.w};
#pragma unroll
        for (int u = 0; u < 4; u++) {
            if (dv[u] >= lo && dv[u] < hi) {
                int k = dv[u] - lo;
                atomicAdd(&hin[k >> 1], 1u << ((k & 1) * 16));
            }
            if (sv[u] >= lo && sv[u] < hi) {
                int k = sv[u] - lo;
                atomicAdd(&hout[k >> 1], 1u << ((k & 1) * 16));
            }
        }
    }
    __syncthreads();
    int n = hi - lo;
    for (int i = threadIdx.x; i < n; i += 256) {
        cnt_in[(size_t)b * NNODES + lo + i]  = (hin[i >> 1]  >> ((i & 1) * 16)) & 0xFFFF;
        cnt_out[(size_t)b * NNODES + lo + i] = (hout[i >> 1] >> ((i & 1) * 16)) & 0xFFFF;
    }
}

// Fused: totals over slices (incnt/outcnt) + block-local exclusive scan of
// incnt (excl, bsum). 196-block geometry.
__global__ __launch_bounds__(256) void reduce_scan_kernel(const int* __restrict__ cnt_in,
                                                          const int* __restrict__ cnt_out,
                                                          int* __restrict__ incnt,
                                                          int* __restrict__ outcnt,
                                                          int* __restrict__ excl,
                                                          int* __restrict__ bsum, int N) {
    __shared__ int sh[256];
    int t = threadIdx.x;
    int g = blockIdx.x * 256 + t;
    int a = 0, b = 0;
    if (g < N) {
        for (int x = 0; x < NSLICE; x++) {
            a += cnt_in[(size_t)x * NNODES + g];
            b += cnt_out[(size_t)x * NNODES + g];
        }
        incnt[g] = a;
        outcnt[g] = b;
    }
    int v = a;                        // 0 for g >= N
    sh[t] = v;
    __syncthreads();
    for (int off = 1; off < 256; off <<= 1) {
        int u = 0;
        if (t >= off) u = sh[t - off];
        __syncthreads();
        sh[t] += u;
        __syncthreads();
    }
    if (g < N) excl[g] = sh[t] - v;   // exclusive within block
    if (t == 255) bsum[blockIdx.x] = sh[255];
}

__global__ __launch_bounds__(256) void scan2_kernel(int* __restrict__ bsum, int nb) {
    __shared__ int sh[256];
    int t = threadIdx.x;
    int v = (t < nb) ? bsum[t] : 0;
    sh[t] = v;
    __syncthreads();
    for (int off = 1; off < 256; off <<= 1) {
        int u = 0;
        if (t >= off) u = sh[t - off];
        __syncthreads();
        sh[t] += u;
        __syncthreads();
    }
    if (t < nb) bsum[t] = sh[t] - v;         // exclusive
}

// Fused scan3+base: row_ptr[n] = excl[n]+bsum[n>>8]; per-slice bucket bases
// base_part[b][n] = row_ptr[n] + sum_{b'<b} cnt_in[b'][n].
__global__ __launch_bounds__(256) void base_kernel(const int* __restrict__ excl,
                                                   const int* __restrict__ bsum,
                                                   const int* __restrict__ cnt_in,
                                                   int* __restrict__ row_ptr,
                                                   int* __restrict__ base_part, int N, int E) {
    int n = blockIdx.x * 256 + threadIdx.x;
    if (n == N) row_ptr[N] = E;
    if (n >= N) return;
    int run = excl[n] + bsum[n >> 8];
    row_ptr[n] = run;
    for (int b = 0; b < NSLICE; b++) {
        base_part[(size_t)b * NNODES + n] = run;
        run += cnt_in[(size_t)b * NNODES + n];
    }
}

// Pass2: bucket edges by dst with 64KB LDS int cursors -- zero global
// atomics, 2 blocks/CU. Payload: src (16b) | etype (<<16). Positions unique:
// cursor range for (b,n) is exactly cnt_in[b][n] wide; slice is a function
// of edge index (no scheduling assumption).
__global__ __launch_bounds__(256) void scatter2_kernel(const int* __restrict__ src,
                                                       const int* __restrict__ dst,
                                                       const int* __restrict__ ef,
                                                       const int* __restrict__ base_part,
                                                       int* __restrict__ epay) {
    __shared__ int cur[RS];             // 64 KB
    int b = blockIdx.x, r = blockIdx.y;
    int lo = r * RS;
    int hi = lo + RS; if (hi > NNODES) hi = NNODES;
    int n = hi - lo;
    for (int i = threadIdx.x; i < n; i += 256)
        cur[i] = base_part[(size_t)b * NNODES + lo + i];
    __syncthreads();
    int off = b * SLICE_E;
    const int4* pd = (const int4*)(dst + off);
    const int4* ps = (const int4*)(src + off);
    const int4* pf = (const int4*)(ef + off);
    for (int i = threadIdx.x; i < SLICE_E / 4; i += 256) {
        int4 d = pd[i];
        int4 s = ps[i];
        int4 f = pf[i];
        int dv[4] = {d.x, d.y, d.z, d.w};
        int sv[4] = {s.x, s.y, s.z, s.w};
        int fv[4] = {f.x, f.y, f.z, f.w};
#pragma unroll
        for (int u = 0; u < 4; u++) {
            if (dv[u] >= lo && dv[u] < hi) {
                int pos = atomicAdd(&cur[dv[u] - lo], 1);
                epay[pos] = sv[u] | (fv[u] << 16);
            }
        }
    }
}

// g0 = bf16(feat * src_norm) and af0 = bf16(ALPHA * feat), both row-major
// [N][128] bf16 (256B rows).
__global__ void scale_kernel(const float* __restrict__ feat, const int* __restrict__ outcnt,
                             unsigned* __restrict__ g0, unsigned* __restrict__ af0, int N) {
    int i = blockIdx.x * blockDim.x + threadIdx.x;   // one float4-group (4 cols)
    if (i >= N * 32) return;
    int row = i >> 5;
    int oc = outcnt[row]; if (oc < 1) oc = 1;
    float sn = rsqrtf((float)oc);
    float4 v = ((const float4*)feat)[i];
    uint2 o, a;
    o.x = bf16rne(v.x * sn) | (bf16rne(v.y * sn) << 16);
    o.y = bf16rne(v.z * sn) | (bf16rne(v.w * sn) << 16);
    a.x = bf16rne(v.x * ALPHA) | (bf16rne(v.y * ALPHA) << 16);
    a.y = bf16rne(v.z * ALPHA) | (bf16rne(v.w * ALPHA) << 16);
    ((uint2*)g0)[i] = o;
    ((uint2*)af0)[i] = a;
}

// Half-wave (32 lanes) per dst node; lane holds uint2 = 4 bf16 cols of the
// 256B row. Payloads loaded coalesced in chunks of 32, broadcast via __shfl;
// 12-deep batches; gate fetched at shfl time. Epilogue f32:
// h = dn*agg + af0 (af0 = bf16(ALPHA*feat0)); stores bf16(h*sn) (last: bf16(h)).
__global__ __launch_bounds__(256) void hop_kernel(const unsigned* __restrict__ g_in,
                                                  const unsigned* __restrict__ af0,
                                                  const int* __restrict__ incnt,
                                                  const int* __restrict__ outcnt,
                                                  const float* __restrict__ gate_g,
                                                  const int* __restrict__ row_ptr,
                                                  const int* __restrict__ epay,
                                                  unsigned* __restrict__ g_out,
                                                  int N, int last) {
    __shared__ float gateL[8];
    if (threadIdx.x < 8) gateL[threadIdx.x] = gate_g[threadIdx.x];
    __syncthreads();
    int half = threadIdx.x >> 5;     // 0..7
    int lane = threadIdx.x & 31;
    int node = blockIdx.x * 8 + half;
    if (node >= N) return;
    int beg = row_ptr[node], end = row_ptr[node + 1];
    const uint2* gp = (const uint2*)g_in;            // row = 32 uint2
    float a0 = 0.f, a1 = 0.f, a2 = 0.f, a3 = 0.f;
    for (int base = beg; base < end; base += 32) {
        int n = end - base; if (n > 32) n = 32;
        int p = 0;
        if (lane < n) p = epay[base + lane];
        int j = 0;
        for (; j + 12 <= n; j += 12) {
            float cg[12];
            uint2 v[12];
#pragma unroll
            for (int u = 0; u < 12; u++) {
                int pj = __shfl(p, j + u, 32);
                cg[u] = gateL[(unsigned)pj >> 16];
                v[u] = gp[((unsigned)(pj & 0xFFFF) << 5) + lane];
            }
#pragma unroll
            for (int u = 0; u < 12; u++) {
                a0 += cg[u] * bf_lo(v[u].x); a1 += cg[u] * bf_hi(v[u].x);
                a2 += cg[u] * bf_lo(v[u].y); a3 += cg[u] * bf_hi(v[u].y);
            }
        }
        for (; j + 8 <= n; j += 8) {
            float cg[8];
            uint2 v[8];
#pragma unroll
            for (int u = 0; u < 8; u++) {
                int pj = __shfl(p, j + u, 32);
                cg[u] = gateL[(unsigned)pj >> 16];
                v[u] = gp[((unsigned)(pj & 0xFFFF) << 5) + lane];
            }
#pragma unroll
            for (int u = 0; u < 8; u++) {
                a0 += cg[u] * bf_lo(v[u].x); a1 += cg[u] * bf_hi(v[u].x);
                a2 += cg[u] * bf_lo(v[u].y); a3 += cg[u] * bf_hi(v[u].y);
            }
        }
        for (; j < n; j++) {
            int pj = __shfl(p, j, 32);
            float c = gateL[(unsigned)pj >> 16];
            uint2 v = gp[((unsigned)(pj & 0xFFFF) << 5) + lane];
            a0 += c * bf_lo(v.x); a1 += c * bf_hi(v.x);
            a2 += c * bf_lo(v.y); a3 += c * bf_hi(v.y);
        }
    }
    int ic = incnt[node]; if (ic < 1) ic = 1;
    float dn = rsqrtf((float)ic) * (1.0f - ALPHA);
    uint2 af = ((const uint2*)af0)[((unsigned)node << 5) + lane];
    float h0 = dn * a0 + bf_lo(af.x);
    float h1 = dn * a1 + bf_hi(af.x);
    float h2 = dn * a2 + bf_lo(af.y);
    float h3 = dn * a3 + bf_hi(af.y);
    float sc = 1.0f;
    if (!last) { int oc = outcnt[node]; if (oc < 1) oc = 1; sc = rsqrtf((float)oc); }
    uint2 o;
    o.x = bf16rne(h0 * sc) | (bf16rne(h1 * sc) << 16);
    o.y = bf16rne(h2 * sc) | (bf16rne(h3 * sc) << 16);
    ((uint2*)g_out)[((unsigned)node << 5) + lane] = o;
}

// bf16 MFMA MLP layer: out[N,128] = act(in[N,128] @ W[128,128] + b).
// W pre-converted bf16. Block = 256 thr (4 waves), 64-row tile, full K=128.
// Verified gfx950 layouts: A[m=lane&15][k=quad*8+j], B[k][n=lane&15],
// D col=lane&15, row=quad*4+reg.
#define ASTR 136
__global__ __launch_bounds__(256) void mlp_mfma_kernel(const unsigned short* __restrict__ in,
                                                       const unsigned short* __restrict__ Wb,
                                                       const float* __restrict__ bias,
                                                       void* __restrict__ outp,
                                                       int N, int mode) {  // mode0: gelu+bf16 out; mode1: f32 out
    __shared__ unsigned short As[64 * ASTR];    // 17.4 KB
    __shared__ unsigned short Bs[128 * ASTR];   // 34.8 KB
    int tid = threadIdx.x;
    int row0 = blockIdx.x * 64;
    // stage A: 64 rows x 128 bf16 (clamp rows >= N)
    for (int i = tid; i < 64 * 16; i += 256) {
        int r = i >> 4, c8 = i & 15;
        int gr = row0 + r; if (gr >= N) gr = N - 1;
        uint4 v = *(const uint4*)(in + (size_t)gr * DD + c8 * 8);
        *(uint4*)&As[r * ASTR + c8 * 8] = v;
    }
    // stage B transposed: Bs[n][k] = Wb[k][n] (bf16 already)
    for (int i = tid; i < 128 * 128; i += 256) {
        int k = i >> 7, n = i & 127;
        Bs[n * ASTR + k] = Wb[i];
    }
    __syncthreads();

    int wv = tid >> 6, lane = tid & 63;
    int m = lane & 15, quad = lane >> 4;
    const unsigned short* arow = &As[(16 * wv + m) * ASTR + quad * 8];
    f32x4 acc[8];
#pragma unroll
    for (int t = 0; t < 8; t++) {
        const unsigned short* brow = &Bs[(t * 16 + m) * ASTR + quad * 8];
        f32x4 c = {0.f, 0.f, 0.f, 0.f};
#pragma unroll
        for (int s = 0; s < 4; s++) {
            short8 a = *(const short8*)(arow + s * 32);
            short8 b = *(const short8*)(brow + s * 32);
            c = __builtin_amdgcn_mfma_f32_16x16x32_bf16(a, b, c, 0, 0, 0);
        }
        acc[t] = c;
    }
#pragma unroll
    for (int t = 0; t < 8; t++) {
        float bv = bias[t * 16 + m];
#pragma unroll
        for (int r = 0; r < 4; r++) {
            int grow = row0 + 16 * wv + quad * 4 + r;
            if (grow >= N) continue;
            float v = acc[t][r] + bv;
            size_t oidx = (size_t)grow * DD + t * 16 + m;
            if (mode == 0) {
                v = 0.5f * v * (1.0f + erff(v * 0.70710678118654752f));
                ((unsigned short*)outp)[oidx] = (unsigned short)bf16rne(v);
            } else {
                ((float*)outp)[oidx] = v;
            }
        }
    }
}

extern "C" void kernel_launch(void* const* d_in, const int* in_sizes, int n_in,
                              void* d_out, int out_size, void* d_ws, size_t ws_size,
                              hipStream_t stream) {
    const float* feat = (const float*)d_in[0];
    const int*   e_feat = (const int*)d_in[1];
    const int*   src = (const int*)d_in[2];
    const int*   dst = (const int*)d_in[3];
    const float* emb = (const float*)d_in[4];
    const float* We1 = (const float*)d_in[5];
    const float* be1 = (const float*)d_in[6];
    const float* We2 = (const float*)d_in[7];
    const float* be2 = (const float*)d_in[8];
    const float* W1  = (const float*)d_in[9];
    const float* b1  = (const float*)d_in[10];
    const float* W2  = (const float*)d_in[11];
    const float* b2  = (const float*)d_in[12];
    float* out = (float*)d_out;

    const int N = NNODES, E = NEDGES;
    const int NBLK = (N + 255) / 256;     // 196 scan/reduce blocks
    char* ws = (char*)d_ws;
    size_t off = 0;
    unsigned* ga = (unsigned*)(ws + off);  off += (size_t)N * 256;        // 12.8 MB bf16 state
    unsigned* gb = (unsigned*)(ws + off);  off += (size_t)N * 256;        // 12.8 MB bf16 state
    unsigned* af0 = (unsigned*)(ws + off); off += (size_t)N * 256;        // 12.8 MB bf16 residual
    int*   epay = (int*)(ws + off);        off += (size_t)E * 4;          // 6.4 MB
    int*   row_ptr = (int*)(ws + off);     off += (size_t)(N + 1) * 4;
    int*   excl = (int*)(ws + off);        off += (size_t)N * 4;
    int*   bsum = (int*)(ws + off);        off += 256 * 4;
    int*   cnts = (int*)(ws + off);        off += (size_t)2 * N * 4;      // incnt|outcnt
    int*   cnt_in = (int*)(ws + off);      off += (size_t)NSLICE * N * 4; // 12.8 MB partials
    int*   cnt_out = (int*)(ws + off);     off += (size_t)NSLICE * N * 4; // 12.8 MB partials
    int*   base_part = (int*)(ws + off);   off += (size_t)NSLICE * N * 4; // 12.8 MB bases
    unsigned short* w1b = (unsigned short*)(ws + off); off += (size_t)DD * DD * 2;
    unsigned short* w2b = (unsigned short*)(ws + off); off += (size_t)DD * DD * 2;
    float* gate = (float*)(ws + off);      off += 64;
    int* incnt  = cnts;
    int* outcnt = cnts + N;

    // No memsets needed: hist writes full partial slabs (incl. zeros).
    gate_kernel<<<1, 256, 0, stream>>>(emb, We1, be1, We2, be2, gate);
    wconv_kernel<<<(DD * DD + 255) / 256, 256, 0, stream>>>(W1, W2, w1b, w2b);
    dim3 hg(NSLICE, NRANGE);
    hist_kernel<<<hg, 256, 0, stream>>>(dst, src, cnt_in, cnt_out);
    reduce_scan_kernel<<<NBLK, 256, 0, stream>>>(cnt_in, cnt_out, incnt, outcnt,
                                                 excl, bsum, N);
    scan2_kernel<<<1, 256, 0, stream>>>(bsum, NBLK);
    base_kernel<<<(N + 256) / 256 + 1, 256, 0, stream>>>(excl, bsum, cnt_in,
                                                         row_ptr, base_part, N, E);
    scatter2_kernel<<<hg, 256, 0, stream>>>(src, dst, e_feat, base_part, epay);
    scale_kernel<<<(N * 32 + 255) / 256, 256, 0, stream>>>(feat, outcnt, ga, af0, N);

    const unsigned* gin = ga;
    unsigned* gout = gb;
    for (int k = 0; k < KHOPS; k++) {
        int last = (k == KHOPS - 1);
        hop_kernel<<<(N + 7) / 8, 256, 0, stream>>>(gin, af0, incnt, outcnt, gate,
                                                    row_ptr, epay, gout, N, last);
        gin = gout;
        gout = (gout == ga) ? gb : ga;
    }
    // Final h (unscaled, bf16) is in ga (hop9 writes ga); gb is free -> hidden.
    const unsigned short* hfin = (const unsigned short*)gin;
    unsigned short* hidden = (unsigned short*)gout;
    mlp_mfma_kernel<<<(N + 63) / 64, 256, 0, stream>>>(hfin, w1b, b1, hidden, N, 0);
    mlp_mfma_kernel<<<(N + 63) / 64, 256, 0, stream>>>(hidden, w2b, b2, out, N, 1);
}